// Round 9
// baseline (383.772 us; speedup 1.0000x reference)
//
#include <hip/hip_runtime.h>
#include <hip/hip_bf16.h>

#define B_ 32
#define N_ 8192
#define DI_ 128
#define D_ 512
#define NC_ 1000
#define TN_ 128          // items per output tile (per block)
#define SN_ 16           // items per sub-tile (4-wave k_main)
#define NSUB_ 8          // sub-tiles per block
#define NT_ 64           // tiles = N_/TN_
#define XROW_ 136        // x_lds row stride in shorts (pad +8)

typedef short s8v __attribute__((ext_vector_type(8)));
typedef float f4v __attribute__((ext_vector_type(4)));

__device__ __forceinline__ unsigned short f2bf(float f){
  union { float f; unsigned u; } c; c.f = f;
  unsigned r = c.u + 0x7fffu + ((c.u >> 16) & 1u);
  return (unsigned short)(r >> 16);
}

__device__ __forceinline__ unsigned pk2bf(float a, float b){
  float2 f; f.x = a; f.y = b;
  __hip_bfloat162 h = __float22bfloat162_rn(f);
  union { __hip_bfloat162 h; unsigned u; } c; c.h = h;
  return c.u;
}

// exact GELU: 0.5x(1+erf(x/sqrt2)); Abramowitz-Stegun 7.1.26, |err| <= 1.5e-7
__device__ __forceinline__ float gelu_f(float x){
  float ax = fabsf(x) * 0.70710678118654752f;
  float t = __builtin_amdgcn_rcpf(1.0f + 0.3275911f * ax);
  float poly = ((((1.061405429f*t - 1.453152027f)*t + 1.421413741f)*t
                 - 0.284496736f)*t + 0.254829592f)*t;
  float e = __expf(-ax*ax);
  float erf_ax = 1.0f - poly*e;
  erf_ax = (x >= 0.0f) ? erf_ax : -erf_ax;
  return 0.5f * x * (1.0f + erf_ax);
}

__device__ __forceinline__ float wsum64(float v){
  #pragma unroll
  for (int off = 32; off; off >>= 1) v += __shfl_xor(v, off, 64);
  return v;
}

// ---------------- prep3: w1 pack + 2 transposes + 3 folded fp32 GEMMs, one launch ----------------
// blocks 0..127  : pack psi_x_w1 -> w1p (bf16 MFMA fragment order)
// blocks 128..191: transpose phi_w1 [512][512] -> pw1T
// blocks 192..319: transpose phi_w2 [1000][512] -> pw2T [512][1000]
// blocks 320..383: KW2[d][t]   = sum_j k_w[d][j]*w2[j][t]                  (NN GEMM)
// blocks 384..447: QW2qT[k][j] = sum_i q_w[j][i]*w2q[i][k]; row512 = qbc   (TN GEMM + bias fold)
// blocks 448..511: VW2T[k][t]  = sum_i v_w[t][i]*w2[i][k];  row512 = zc    (TN GEMM + bias fold)
__global__ __launch_bounds__(512)
void k_prep3(const float* __restrict__ w1,  unsigned short* __restrict__ w1p,
             const float* __restrict__ pw1, float* __restrict__ pw1T,
             const float* __restrict__ pw2, float* __restrict__ pw2T,
             const float* __restrict__ kw,  const float* __restrict__ w2,
             float* __restrict__ KW2,
             const float* __restrict__ qw,  const float* __restrict__ w2q,
             const float* __restrict__ b2q, const float* __restrict__ qb,
             float* __restrict__ QW2qT,
             const float* __restrict__ vw,  const float* __restrict__ b2x,
             const float* __restrict__ vb,  float* __restrict__ VW2T){
  const int t = threadIdx.x;
  const int bid = blockIdx.x;
  __shared__ float As[64][65];   // odd stride: conflict-free strided reads
  __shared__ float Bs[64][68];   // mult-of-4 stride: float4-aligned rows
  __shared__ float bsv[64];

  if (bid < 128){
    const int i = bid*512 + t;                 // < 65536 = D_*DI_
    const int j = i / DI_, kc = i % DI_;
    const int kk = kc >> 5, q = (kc >> 3) & 3, s = kc & 7;
    w1p[((kk*D_ + j)*4 + q)*8 + s] = f2bf(w1[i]);
    return;
  }
  const int r0 = t >> 6;                       // 0..7
  const int c  = t & 63;
  if (bid < 192){                              // pw1 transpose (8x8 tiles of 64x64)
    const int id = bid - 128;
    const int to = id >> 3, tk = id & 7;
    #pragma unroll
    for (int i = 0; i < 8; ++i){
      const int r = r0 + i*8;
      As[r][c] = pw1[(size_t)(to*64 + r)*D_ + tk*64 + c];
    }
    __syncthreads();
    #pragma unroll
    for (int i = 0; i < 8; ++i){
      const int r = r0 + i*8;
      pw1T[(size_t)(tk*64 + r)*D_ + to*64 + c] = As[c][r];
    }
    return;
  }
  if (bid < 320){                              // pw2 transpose (16x8 tiles)
    const int id = bid - 192;
    const int tr = id >> 3, tk = id & 7;
    #pragma unroll
    for (int i = 0; i < 8; ++i){
      const int r = r0 + i*8;
      const int ro = tr*64 + r;
      As[r][c] = (ro < NC_) ? pw2[(size_t)ro*D_ + tk*64 + c] : 0.f;
    }
    __syncthreads();
    #pragma unroll
    for (int i = 0; i < 8; ++i){
      const int r = r0 + i*8;
      const int co = tr*64 + c;
      if (co < NC_)
        pw2T[(size_t)(tk*64 + r)*NC_ + co] = As[c][r];
    }
    return;
  }
  // ---- GEMM blocks ----
  const int id = bid - 320;                    // 0..191
  const int mi = id >> 6;                      // 0 KW2(NN), 1 QW2qT(TN), 2 VW2T(TN)
  const int tt = id & 63;
  const int rt = tt >> 3, ct = tt & 7;
  const float* A    = (mi==0) ? kw  : (mi==1) ? qw  : vw;
  const float* B    = (mi==1) ? w2q : w2;
  const float* bvec = (mi==1) ? b2q : b2x;
  const float* badd = (mi==1) ? qb  : vb;
  float* C          = (mi==0) ? KW2 : (mi==1) ? QW2qT : VW2T;
  const bool nn = (mi == 0);
  const int arow0 = (nn ? rt : ct) * 64;
  const int bcol0 = (nn ? ct : rt) * 64;

  float acc[8] = {0.f,0.f,0.f,0.f,0.f,0.f,0.f,0.f};
  float ba0 = 0.f, ba1 = 0.f;

  for (int i0 = 0; i0 < 512; i0 += 64){
    #pragma unroll
    for (int i = 0; i < 8; ++i){
      const int r = r0 + i*8;
      As[r][c] = A[(size_t)(arow0 + r)*512 + i0 + c];
      Bs[r][c] = B[(size_t)(i0 + r)*512 + bcol0 + c];
    }
    if (t < 64) bsv[t] = (mi != 0) ? bvec[i0 + t] : 0.f;
    __syncthreads();
    if (nn){
      // C[r][c] = sum A[r][i]B[i][c]; thread: r = rg*2+{0,1}, c = cg*4..+3
      const int cg = t & 15, rg = t >> 4;
      #pragma unroll 4
      for (int ii = 0; ii < 64; ++ii){
        const float a0 = As[rg*2][ii], a1 = As[rg*2+1][ii];
        const float4 bv = *(const float4*)&Bs[ii][cg*4];
        acc[0] += a0*bv.x; acc[1] += a0*bv.y; acc[2] += a0*bv.z; acc[3] += a0*bv.w;
        acc[4] += a1*bv.x; acc[5] += a1*bv.y; acc[6] += a1*bv.z; acc[7] += a1*bv.w;
      }
    } else {
      // T[r][c] = sum A[c][i]B[i][r]; thread: c = cg*2+{0,1}, r = rg*4..+3
      const int cg = t & 31, rg = t >> 5;
      #pragma unroll 4
      for (int ii = 0; ii < 64; ++ii){
        const float a0 = As[cg*2][ii], a1 = As[cg*2+1][ii];
        const float4 bv = *(const float4*)&Bs[ii][rg*4];
        acc[0] += bv.x*a0; acc[1] += bv.y*a0; acc[2] += bv.z*a0; acc[3] += bv.w*a0;
        acc[4] += bv.x*a1; acc[5] += bv.y*a1; acc[6] += bv.z*a1; acc[7] += bv.w*a1;
        if (rg == 0){ const float bb = bsv[ii]; ba0 += a0*bb; ba1 += a1*bb; }
      }
    }
    __syncthreads();
  }
  if (nn){
    const int cg = t & 15, rg = t >> 4;
    #pragma unroll
    for (int p = 0; p < 2; ++p){
      float4 o; o.x = acc[p*4]; o.y = acc[p*4+1]; o.z = acc[p*4+2]; o.w = acc[p*4+3];
      *(float4*)&C[(size_t)(rt*64 + rg*2 + p)*512 + ct*64 + cg*4] = o;
    }
  } else {
    const int cg = t & 31, rg = t >> 5;
    #pragma unroll
    for (int p = 0; p < 4; ++p){
      float2 o; o.x = acc[p]; o.y = acc[4+p];     // acc[j*4+p]: j=c-offset, p=r-offset
      *(float2*)&C[(size_t)(rt*64 + rg*4 + p)*512 + ct*64 + cg*2] = o;
    }
    if (rt == 0 && rg == 0){
      float* Cb = C + 512*512;
      Cb[ct*64 + cg*2]     = ba0 + badd[ct*64 + cg*2];
      Cb[ct*64 + cg*2 + 1] = ba1 + badd[ct*64 + cg*2 + 1];
    }
  }
}

// ---------------- generic wide batched GEMV stage (FROZEN from r8) ----------------
template<int J, bool ACT, bool HASB>
__global__ __launch_bounds__(512)
void k_gemv(const float* __restrict__ WT, const float* __restrict__ X,
            const float* __restrict__ bias, float* __restrict__ Y,
            const float scale){
  const int sl = blockIdx.x, b = blockIdx.y, t = threadIdx.x;
  const int c = t & 63, w = t >> 6;
  __shared__ float xs[D_];
  __shared__ float red[8][64];
  xs[t] = X[(size_t)b*D_ + t];
  __syncthreads();
  const int j = sl*64 + c;
  const float* wp = WT + (size_t)(w*64)*J + j;
  const float* xp = xs + w*64;
  float a0=0.f, a1=0.f, a2=0.f, a3=0.f;
  #pragma unroll
  for (int k = 0; k < 64; k += 4){
    a0 += wp[(size_t)(k+0)*J] * xp[k+0];
    a1 += wp[(size_t)(k+1)*J] * xp[k+1];
    a2 += wp[(size_t)(k+2)*J] * xp[k+2];
    a3 += wp[(size_t)(k+3)*J] * xp[k+3];
  }
  red[w][c] = (a0+a1)+(a2+a3);
  __syncthreads();
  if (w == 0 && j < J){
    float s = ((red[0][c]+red[1][c])+(red[2][c]+red[3][c]))
            + ((red[4][c]+red[5][c])+(red[6][c]+red[7][c]));
    s = s * scale;
    if (HASB) s += bias[j];
    Y[(size_t)b*J + j] = ACT ? gelu_f(s) : s;
  }
}

// query head: qv[j] = sum_k QW2qT[k][j]*gelu(xq*w1q+b1q)[k] + qbc[j]  (FROZEN from r8)
__global__ __launch_bounds__(512)
void k_gemv_q1(const float* __restrict__ xq,  const float* __restrict__ w1q,
               const float* __restrict__ b1q,
               const float* __restrict__ WT,  const float* __restrict__ bias,
               float* __restrict__ Y){
  const int sl = blockIdx.x, b = blockIdx.y, t = threadIdx.x;
  const int c = t & 63, w = t >> 6;
  __shared__ float xs[D_];
  __shared__ float red[8][64];
  xs[t] = gelu_f(xq[b] * w1q[t] + b1q[t]);
  __syncthreads();
  const int j = sl*64 + c;
  const float* wp = WT + (size_t)(w*64)*D_ + j;
  const float* xp = xs + w*64;
  float a0=0.f, a1=0.f, a2=0.f, a3=0.f;
  #pragma unroll
  for (int k = 0; k < 64; k += 4){
    a0 += wp[(size_t)(k+0)*D_] * xp[k+0];
    a1 += wp[(size_t)(k+1)*D_] * xp[k+1];
    a2 += wp[(size_t)(k+2)*D_] * xp[k+2];
    a3 += wp[(size_t)(k+3)*D_] * xp[k+3];
  }
  red[w][c] = (a0+a1)+(a2+a3);
  __syncthreads();
  if (w == 0){
    float s = ((red[0][c]+red[1][c])+(red[2][c]+red[3][c]))
            + ((red[4][c]+red[5][c])+(red[6][c]+red[7][c]));
    Y[(size_t)b*D_ + j] = s + bias[j];
  }
}

// ---------------- main: 256 thr (4 waves), wave owns 128 j-cols, SN=16, NSUB=8 ----------------
// r8 lesson: 8-wave blocks at 140 regs/wave round down to 1 block/CU (22% occ).
// 4-wave blocks pack 3/CU at ~150 regs -> 12 waves/CU. Same MFMA work per wave.
__global__ __launch_bounds__(256, 2)
void k_main(const float* __restrict__ x,                 // [B,N,DI]
            const unsigned short* __restrict__ w1p,      // packed bf16
            const float* __restrict__ b1,
            const float* __restrict__ qkw2,              // [B,D]
            float* __restrict__ part,                    // [B,NT,D]
            float* __restrict__ esum){                   // [B,NT]
  const int tile = blockIdx.x;       // 0..63
  const int b = blockIdx.y;          // 0..31
  const int t = threadIdx.x;         // 0..255
  const int lane = t & 63;
  const int wid = t >> 6;            // 0..3
  const int ln = lane & 15;
  const int q  = lane >> 4;          // 0..3

  __shared__ unsigned short x_lds[2][SN_ * XROW_];  // 2 x 4352 B
  __shared__ float s_ws[4][SN_];                    // 256 B
  __shared__ float e_lds[SN_];                      // 64 B
  __shared__ float sb1[D_];                         // 2048 B
  __shared__ float sq2[D_];                         // 2048 B

  const int jb = wid * 128;             // this wave's 128-col j block
  const unsigned short* w1base = w1p + (jb + ln)*32 + q*8;
  const float* xbase = x + ((size_t)b * N_ + tile * TN_) * DI_;

  sb1[t] = b1[t];            sb1[t+256] = b1[t+256];
  sq2[t] = qkw2[b*D_ + t];   sq2[t+256] = qkw2[b*D_ + t+256];
  {
    const float4* x4 = (const float4*)xbase;
    #pragma unroll
    for (int i = 0; i < 2; ++i){
      const int f = i*256 + t;            // 512 float4 per sub-tile (16 rows x 32)
      float4 v = x4[f];
      const int m = f >> 5;
      const int k = (f & 31) << 2;
      uint2 pk;
      pk.x = pk2bf(v.x, v.y);
      pk.y = pk2bf(v.z, v.w);
      *(uint2*)&x_lds[0][m*XROW_ + k] = pk;
    }
  }
  __syncthreads();

  f4v zacc[8];
  #pragma unroll
  for (int i = 0; i < 8; ++i) zacc[i] = (f4v){0.f,0.f,0.f,0.f};
  float etot = 0.f;

  for (int s = 0; s < NSUB_; ++s){
    const unsigned short* xb = x_lds[s & 1];

    f4v acc[8];
    #pragma unroll
    for (int i = 0; i < 8; ++i) acc[i] = (f4v){0.f,0.f,0.f,0.f};

    // ---- GEMM1: h1^T[j,m] over this wave's 128 j, 16 m ----
    #pragma unroll
    for (int kk = 0; kk < 4; ++kk){
      const int k = kk*32 + q*8;
      const s8v bx = *(const s8v*)&xb[ln*XROW_ + k];
      #pragma unroll
      for (int jt = 0; jt < 8; ++jt){
        const s8v aw = *(const s8v*)(w1base + kk*(D_*32) + jt*(16*32));
        acc[jt] = __builtin_amdgcn_mfma_f32_16x16x32_bf16(aw, bx, acc[jt], 0,0,0);
      }
    }

    // ---- prefetch next sub-tile ----
    float4 pv0, pv1;
    if (s + 1 < NSUB_){
      const float4* x4 = (const float4*)(xbase + (size_t)(s+1)*SN_*DI_);
      pv0 = x4[t];
      pv1 = x4[256 + t];
    }

    // ---- bias + GELU (in place) + score partial over this wave's 128 j ----
    float sp = 0.f;
    #pragma unroll
    for (int jt = 0; jt < 8; ++jt){
      const f4v bv = *(const f4v*)&sb1[jb + jt*16 + q*4];
      const f4v qv = *(const f4v*)&sq2[jb + jt*16 + q*4];
      f4v a = acc[jt];
      a[0] = gelu_f(a[0] + bv[0]);
      a[1] = gelu_f(a[1] + bv[1]);
      a[2] = gelu_f(a[2] + bv[2]);
      a[3] = gelu_f(a[3] + bv[3]);
      acc[jt] = a;
      sp += qv[0]*a[0] + qv[1]*a[1] + qv[2]*a[2] + qv[3]*a[3];
    }
    sp += __shfl_xor(sp, 16, 64);
    sp += __shfl_xor(sp, 32, 64);
    if (q == 0) s_ws[wid][ln] = sp;     // m = ln

    // ---- write prefetched x to the other buffer ----
    if (s + 1 < NSUB_){
      unsigned short* xn = &x_lds[(s+1) & 1][0];
      int f = t, m = f >> 5, k = (f & 31) << 2;
      uint2 pk;
      pk.x = pk2bf(pv0.x, pv0.y);
      pk.y = pk2bf(pv0.z, pv0.w);
      *(uint2*)&xn[m*XROW_ + k] = pk;
      f = 256 + t; m = f >> 5; k = (f & 31) << 2;
      pk.x = pk2bf(pv1.x, pv1.y);
      pk.y = pk2bf(pv1.z, pv1.w);
      *(uint2*)&xn[m*XROW_ + k] = pk;
    }
    __syncthreads();     // (A)

    if (t < SN_){
      float sc = 0.f;
      #pragma unroll
      for (int w = 0; w < 4; ++w) sc += s_ws[w][t];
      e_lds[t] = __expf(sc);
    }
    __syncthreads();     // (B)

    if (wid == 0){
      float v = (lane < SN_) ? e_lds[lane] : 0.f;
      etot += wsum64(v);
    }

    {
      const float em = e_lds[ln];
      #pragma unroll
      for (int jt = 0; jt < 8; ++jt){
        const f4v a = acc[jt];
        #pragma unroll
        for (int r = 0; r < 4; ++r)
          zacc[jt][r] += em * a[r];
      }
    }
  }

  if (t == 0) esum[b*NT_ + tile] = etot;

  #pragma unroll
  for (int jt = 0; jt < 8; ++jt){
    #pragma unroll
    for (int r = 0; r < 4; ++r){
      float v = zacc[jt][r];
      v += __shfl_xor(v, 1, 64);
      v += __shfl_xor(v, 2, 64);
      v += __shfl_xor(v, 4, 64);
      v += __shfl_xor(v, 8, 64);
      zacc[jt][r] = v;
    }
    if (ln == 0){
      float4 o; o.x = zacc[jt][0]; o.y = zacc[jt][1]; o.z = zacc[jt][2]; o.w = zacc[jt][3];
      *(float4*)&part[((size_t)(b*NT_ + tile))*D_ + jb + jt*16 + q*4] = o;
    }
  }
}

// u[b][col] = (1/sum e) * sum_tl part[b][tl][col];  grid (32,4) x 128  (FROZEN)
__global__ __launch_bounds__(128)
void k_fu(const float* __restrict__ part, const float* __restrict__ esum,
          float* __restrict__ u){
  const int b = blockIdx.x, sl = blockIdx.y, t = threadIdx.x;
  float p = esum[b*NT_ + (t & 63)];
  p = wsum64(p);
  const float linv = 1.0f / p;
  const int col = sl*128 + t;
  const float* pb = part + (size_t)b*NT_*D_ + col;
  float s = 0.f;
  #pragma unroll 8
  for (int tl = 0; tl < NT_; ++tl) s += pb[tl*D_];
  u[b*D_ + col] = s * linv;
}

extern "C" void kernel_launch(void* const* d_in, const int* in_sizes, int n_in,
                              void* d_out, int out_size, void* d_ws, size_t ws_size,
                              hipStream_t stream) {
  (void)in_sizes; (void)n_in; (void)out_size; (void)ws_size;
  const float* x_items  = (const float*)d_in[0];
  const float* x_query  = (const float*)d_in[1];
  const float* psi_x_w1 = (const float*)d_in[2];
  const float* psi_x_b1 = (const float*)d_in[3];
  const float* psi_x_w2 = (const float*)d_in[4];
  const float* psi_x_b2 = (const float*)d_in[5];
  const float* psi_q_w1 = (const float*)d_in[6];
  const float* psi_q_b1 = (const float*)d_in[7];
  const float* psi_q_w2 = (const float*)d_in[8];
  const float* psi_q_b2 = (const float*)d_in[9];
  const float* q_w      = (const float*)d_in[10];
  const float* q_b      = (const float*)d_in[11];
  const float* k_w      = (const float*)d_in[12];
  // k_b (d_in[13]) unused: constant score shift cancels in softmax
  const float* v_w      = (const float*)d_in[14];
  const float* v_b      = (const float*)d_in[15];
  const float* phi_w1   = (const float*)d_in[16];
  const float* phi_b1   = (const float*)d_in[17];
  const float* phi_w2   = (const float*)d_in[18];
  const float* phi_b2   = (const float*)d_in[19];
  float* out = (float*)d_out;

  // Workspace (max end 10,645,504 B < r5-proven 11,739,136):
  //  qvg aliases part (consumed before k_main writes part);
  //  ub/zb/hb alias KW2 (consumed before k_main).
  char* ws = (char*)d_ws;
  unsigned short* w1p = (unsigned short*)(ws);                 // 131072
  float* qkw2  = (float*)(ws + 131072);                        // 65536
  float* part  = (float*)(ws + 196608);                        // 4194304
  float* qvg   = (float*)(ws + 196608);                        // 65536 (alias: part)
  float* esum  = (float*)(ws + 4390912);                       // 8192
  float* KW2   = (float*)(ws + 4399104);                       // 1048576
  float* ub    = (float*)(ws + 4399104);                       // 65536 (alias: KW2)
  float* zb    = (float*)(ws + 4464640);                       // 65536 (alias: KW2)
  float* hb    = (float*)(ws + 4530176);                       // 65536 (alias: KW2)
  float* QW2qT = (float*)(ws + 5447680);                       // 1050624 ([513][512])
  float* VW2T  = (float*)(ws + 6498304);                       // 1050624 ([513][512])
  float* pw1T  = (float*)(ws + 7548928);                       // 1048576
  float* pw2T  = (float*)(ws + 8597504);                       // 2048000

  const float SC = 0.04419417382415922f;   // 512^-0.5

  hipLaunchKernelGGL(k_prep3, dim3(512), dim3(512), 0, stream,
                     psi_x_w1, w1p, phi_w1, pw1T, phi_w2, pw2T,
                     k_w, psi_x_w2, KW2,
                     q_w, psi_q_w2, psi_q_b2, q_b, QW2qT,
                     v_w, psi_x_b2, v_b, VW2T);
  // query: 2 launches (folds removed 2 stages)
  hipLaunchKernelGGL(k_gemv_q1, dim3(8, 32), dim3(512), 0, stream,
                     x_query, psi_q_w1, psi_q_b1, QW2qT, QW2qT + 512*512, qvg);
  hipLaunchKernelGGL(HIP_KERNEL_NAME(k_gemv<D_, false, false>), dim3(8, 32), dim3(512), 0, stream,
                     KW2, qvg, q_b /*unused*/, qkw2, SC);
  hipLaunchKernelGGL(k_main, dim3(NT_, B_), dim3(256), 0, stream,
                     x_items, w1p, psi_x_b1, qkw2, part, esum);
  // tail: 4 launches (fold removed u2 stage)
  hipLaunchKernelGGL(k_fu, dim3(32, 4), dim3(128), 0, stream,
                     part, esum, ub);
  hipLaunchKernelGGL(HIP_KERNEL_NAME(k_gemv<D_, false, true>), dim3(8, 32), dim3(512), 0, stream,
                     VW2T, ub, VW2T + 512*512, zb, 1.0f);
  hipLaunchKernelGGL(HIP_KERNEL_NAME(k_gemv<D_, true, true>), dim3(8, 32), dim3(512), 0, stream,
                     pw1T, zb, phi_b1, hb, 1.0f);
  hipLaunchKernelGGL(HIP_KERNEL_NAME(k_gemv<NC_, false, true>), dim3(16, 32), dim3(512), 0, stream,
                     pw2T, hb, phi_b2, out, 1.0f);
}